// Round 4
// baseline (196.663 us; speedup 1.0000x reference)
//
#include <hip/hip_runtime.h>
#include <math.h>

#define BATCH 32
#define CIn   32
#define COut  64
#define MODES 2112

typedef __attribute__((ext_vector_type(8))) short bf16x8;
typedef __attribute__((ext_vector_type(4))) float f32x4;

// ws byte offsets
#define OB_T1F  0u           // 20480 ushort = 40960 B
#define OB_A2F  40960u       // 32768 ushort = 65536 B
#define OB_Y    106496u      // 262144*66*2 = 34603008 B
#define OB_XTB  34709504u    // 1024*4224*2 = 8650752 B   [b][i][m][reim] bf16, signs folded
#define OB_PART 43360256u    // 1056*2048*4 = 8650752 B
// end 52011008 B

__device__ __forceinline__ ushort f2bf(float f) {
    union { float f; uint u; } v; v.f = f;
    uint r = (v.u + 0x7FFFu + ((v.u >> 16) & 1u)) >> 16;
    return (ushort)r;
}

__device__ __forceinline__ bf16x8 cvt8(f32x4 lo, f32x4 hi) {
    bf16x8 r;
    r[0] = (short)f2bf(lo[0]); r[1] = (short)f2bf(lo[1]);
    r[2] = (short)f2bf(lo[2]); r[3] = (short)f2bf(lo[3]);
    r[4] = (short)f2bf(hi[0]); r[5] = (short)f2bf(hi[1]);
    r[6] = (short)f2bf(hi[2]); r[7] = (short)f2bf(hi[3]);
    return r;
}

// n-tile base columns (66 cols as 5 16-wide tiles; tile 4 = cols 50..65)
#define NB0 0
#define NB1 16
#define NB2 32
#define NB3 48
#define NB4 50

// ---------------------------------------------------------------------------
// Twiddle tables in MFMA-fragment-linear layout (unchanged from round 3).
// ---------------------------------------------------------------------------
__global__ void fno_tw(ushort* __restrict__ T1f, ushort* __restrict__ A2f) {
    const int nb[5] = {NB0, NB1, NB2, NB3, NB4};
    int idx = blockIdx.x * 256 + threadIdx.x;
    const float w0 = 6.28318530717958647692f / 256.0f;
    if (idx < 20480) {
        int i = idx & 7, l = (idx >> 3) & 63, ct = idx >> 9;
        int c = ct / 5, t = ct - 5 * c;
        int k = 32 * c + 8 * (l >> 4) + i;
        int n = nb[t] + (l & 15);
        int ky = n >> 1, s = n & 1;
        int m = (k * ky) & 255;
        float v = s ? -sinf(w0 * (float)m) : cosf(w0 * (float)m);
        T1f[idx] = f2bf(v * (1.0f / 65536.0f));
    }
    if (idx < 32768) {
        int i = idx & 7, l = (idx >> 3) & 63, cm = idx >> 9;
        int c = cm >> 2, mt = cm & 3;
        int kk = 32 * c + 8 * (l >> 4) + i;
        int kx = mt * 16 + (l & 15);
        int x = kk >> 1, s = kk & 1;
        int kxa = (kx < 32) ? kx : kx + 192;
        int m = (x * kxa) & 255;
        float v = s ? -sinf(w0 * (float)m) : cosf(w0 * (float)m);
        A2f[idx] = f2bf(v);
    }
}

// ---------------------------------------------------------------------------
// K1: Y = X @ T1 (M=262144, K=256, N=66). LDS-staged via global_load_lds
// (2-phase dbuf, T3-min). A-tile XOR-swizzled at 16B granularity via
// pre-swizzled global source (linear LDS dest, rule #21).
// Block = 256 thr (4 waves); wave owns one 16-row m-tile; 8 strips/block.
// ---------------------------------------------------------------------------
#define MFMA5(CG, AV)                                                              \
    acc0 = __builtin_amdgcn_mfma_f32_16x16x32_bf16((AV), bfr[(CG)*5+0], acc0, 0,0,0); \
    acc1 = __builtin_amdgcn_mfma_f32_16x16x32_bf16((AV), bfr[(CG)*5+1], acc1, 0,0,0); \
    acc2 = __builtin_amdgcn_mfma_f32_16x16x32_bf16((AV), bfr[(CG)*5+2], acc2, 0,0,0); \
    acc3 = __builtin_amdgcn_mfma_f32_16x16x32_bf16((AV), bfr[(CG)*5+3], acc3, 0,0,0); \
    acc4 = __builtin_amdgcn_mfma_f32_16x16x32_bf16((AV), bfr[(CG)*5+4], acc4, 0,0,0);

// stage chunk (64 rows x 64 cols fp32 = 16KB) into BUF; 4 insts/thread.
// LDS slot (rr, sp) receives global col-slot (sp ^ (rr&7))  [involution]
#define STAGE(BUF, ROW0, CC) do {                                                  \
    _Pragma("unroll")                                                              \
    for (int j = 0; j < 4; ++j) {                                                  \
        int rr_ = ((w * 4 + j) << 2) + (lane >> 4);                                \
        int sg_ = (lane & 15) ^ (rr_ & 7);                                         \
        const float* gp_ = x + ((size_t)((ROW0) + rr_)) * 256 + (CC) * 64 + (sg_ << 2); \
        char* lp_ = (char*)(BUF) + ((w * 4 + j) << 10);                            \
        __builtin_amdgcn_global_load_lds(                                          \
            (const __attribute__((address_space(1))) unsigned int*)gp_,            \
            (__attribute__((address_space(3))) unsigned int*)lp_, 16, 0, 0);       \
    } } while (0)

__global__ __launch_bounds__(256, 2)
void fno_gemm1(const float* __restrict__ x, const ushort* __restrict__ T1f,
               ushort* __restrict__ Y) {
    __shared__ float smx[2][4096];   // 2 x 16KB chunk buffers
    const int tid  = threadIdx.x;
    const int lane = tid & 63;
    const int w    = tid >> 6;
    const int r0   = lane & 15;
    const int g    = lane >> 4;
    const int blk  = blockIdx.x;

    bf16x8 bfr[40];
    const bf16x8* bp = (const bf16x8*)T1f;
#pragma unroll
    for (int q = 0; q < 40; ++q) bfr[q] = bp[q * 64 + lane];

    const int rr = (w << 4) + r0;     // A-read row within chunk
    const int xr = rr & 7;            // read-side swizzle key

    // prologue: stage strip 0, chunk 0 into buf 0
    STAGE(&smx[0][0], (size_t)blk * 512, 0);
    __syncthreads();

    for (int sl = 0; sl < 8; ++sl) {
        const size_t row0 = ((size_t)blk * 8 + sl) * 64;
        f32x4 acc0 = {0,0,0,0}, acc1 = {0,0,0,0}, acc2 = {0,0,0,0},
              acc3 = {0,0,0,0}, acc4 = {0,0,0,0};
#pragma unroll
        for (int c = 0; c < 4; ++c) {
            // stage next chunk into other buffer
            if (sl < 7 || c < 3) {
                int sl2 = (c == 3) ? sl + 1 : sl;
                size_t row0n = ((size_t)blk * 8 + sl2) * 64;
                STAGE(&smx[(c + 1) & 1][0], row0n, (c + 1) & 3);
            }
            // compute chunk c from buf[c&1]
            const float* rowp = &smx[c & 1][rr * 64];
#pragma unroll
            for (int cl = 0; cl < 2; ++cl) {
                int s0 = (cl << 3) + (g << 1);
                f32x4 lo = *(const f32x4*)&rowp[((s0) ^ xr) << 2];
                f32x4 hi = *(const f32x4*)&rowp[((s0 + 1) ^ xr) << 2];
                bf16x8 a = cvt8(lo, hi);
                if (cl == 0) { MFMA5(2 * c + 0, a); }
                else         { MFMA5(2 * c + 1, a); }
            }
            if (c == 3) {
                // strip complete: fold + store Y for m-tile (strip*4 + w)
                size_t mtg = ((size_t)blk * 8 + sl) * 4 + w;
                ushort* yp = Y + mtg * (16 * 66);
#pragma unroll
                for (int j = 0; j < 4; ++j) {
                    int row = 4 * g + j;
                    yp[row * 66 + NB0 + r0] = f2bf(acc0[j]);
                    yp[row * 66 + NB1 + r0] = f2bf(acc1[j]);
                    yp[row * 66 + NB2 + r0] = f2bf(acc2[j]);
                    yp[row * 66 + NB3 + r0] = f2bf(acc3[j]);
                    if (r0 >= 14) yp[row * 66 + NB4 + r0] = f2bf(acc4[j]);
                }
            }
            __syncthreads();   // drains vmcnt (staged next chunk) + lgkmcnt
        }
    }
}

// ---------------------------------------------------------------------------
// K2: per plane XT[64,66] = A2[64,512] @ B2[512,66]; B2 from Y (transposed,
// XOR-swizzled LDS). Output: bf16 XTb[b][i][m][reim] with mode-sum weights
// and the (-XTi) sign folded; staged through LDS for coalesced store.
// ---------------------------------------------------------------------------
__global__ __launch_bounds__(256)
void fno_gemm2(const ushort* __restrict__ Y, const ushort* __restrict__ A2f,
               ushort* __restrict__ XTb) {
    __shared__ ushort B2t[66 * 512];          // 67.6 KB; reused as xtl[4224] later
    const int tid = threadIdx.x;
    const int p   = blockIdx.x;

    const ushort* yp = Y + (size_t)p * (256 * 66);
    uint* b32 = (uint*)B2t;
    for (int e = tid; e < 8448; e += 256) {    // e = x*33 + ky
        int xx = e / 33;
        int ky = e - 33 * xx;
        uint v = *(const uint*)(yp + xx * 66 + 2 * ky);
        uint yr = v & 0xffffu, yi = v >> 16;
        uint w0 = yr | ((yi ^ 0x8000u) << 16);
        uint w1 = yi | (yr << 16);
        int u = xx >> 2, off = xx & 3;
        int ra = 2 * ky, rb = 2 * ky + 1;
        b32[ra * 256 + ((u ^ (ra & 7)) << 2) + off] = w0;
        b32[rb * 256 + ((u ^ (rb & 7)) << 2) + off] = w1;
    }

    const int lane = tid & 63;
    const int mt   = tid >> 6;
    const int r0   = lane & 15;
    const int g    = lane >> 4;

    bf16x8 af[16];
    const bf16x8* ap = (const bf16x8*)A2f;
#pragma unroll
    for (int c = 0; c < 16; ++c) af[c] = ap[(c * 4 + mt) * 64 + lane];

    __syncthreads();

    const int nb[5] = {NB0, NB1, NB2, NB3, NB4};
    f32x4 acc[5];
#pragma unroll
    for (int t = 0; t < 5; ++t) acc[t] = (f32x4){0, 0, 0, 0};

#pragma unroll
    for (int c = 0; c < 16; ++c) {
#pragma unroll
        for (int t = 0; t < 5; ++t) {
            int row = nb[t] + r0;
            int u = (c << 2) + g;
            bf16x8 b = *(const bf16x8*)&B2t[row * 512 + ((u ^ (row & 7)) << 3)];
            acc[t] = __builtin_amdgcn_mfma_f32_16x16x32_bf16(af[c], b, acc[t], 0, 0, 0);
        }
    }

    __syncthreads();                 // all B2t reads done; reuse as xtl
    ushort* xtl = B2t;
#pragma unroll
    for (int t = 0; t < 5; ++t) {
        int n  = nb[t] + r0;
        int ky = n >> 1, im = n & 1;
#pragma unroll
        for (int j = 0; j < 4; ++j) {
            if (t == 4 && r0 < 14) continue;
            int kx = mt * 16 + 4 * g + j;
            float wgt = (kx < 32) ? ((kx == 0 && ky == 0) ? 1.f : 2.f)
                                  : ((ky == 0) ? 0.f : 2.f);
            if (im) wgt = -wgt;      // fold the (-XTi)*Wi sign
            xtl[kx * 66 + 2 * ky + im] = f2bf(wgt * acc[t][j]);
        }
    }
    __syncthreads();

    const uint4* srcq = (const uint4*)xtl;
    uint4* dstq = (uint4*)(XTb + (size_t)p * 4224);
    for (int e = tid; e < 528; e += 256) dstq[e] = srcq[e];
}

// ---------------------------------------------------------------------------
// K3: out[b,o] = sum_k XTb[b][k] * Wb[k][o], K = 32*4224 = 135168.
// W read directly from global fp32 in fragment order (16B/lane contiguous),
// converted in-register. Split-K: 1056 blocks = (ic, s in 0..32), 4 k-steps.
// ---------------------------------------------------------------------------
__global__ __launch_bounds__(256)
void fno_gemm3(const ushort* __restrict__ XTb, const float* __restrict__ Wr,
               const float* __restrict__ Wi, float* __restrict__ part) {
    const int blk = blockIdx.x;
    const int ic  = blk / 33;
    const int s   = blk - ic * 33;
    const int tid = threadIdx.x;
    const int lane = tid & 63;
    const int w    = tid >> 6;          // n-tile
    const int r0   = lane & 15;
    const int g    = lane >> 4;
    const int o    = (w << 4) + r0;

    const float* wrp = Wr + ((size_t)ic * 64 + o) * 2112 + s * 64 + 4 * g;
    const float* wip = Wi + ((size_t)ic * 64 + o) * 2112 + s * 64 + 4 * g;
    const ushort* a0 = XTb + ((size_t)r0 * 32 + ic) * 4224 + s * 128 + 8 * g;
    const ushort* a1 = a0 + (size_t)16 * 32 * 4224;

    f32x4 acc0 = {0,0,0,0}, acc1 = {0,0,0,0};
#pragma unroll
    for (int st = 0; st < 4; ++st) {
        f32x4 vr = *(const f32x4*)(wrp + st * 16);
        f32x4 vi = *(const f32x4*)(wip + st * 16);
        bf16x8 b;
        b[0] = (short)f2bf(vr[0]); b[1] = (short)f2bf(vi[0]);
        b[2] = (short)f2bf(vr[1]); b[3] = (short)f2bf(vi[1]);
        b[4] = (short)f2bf(vr[2]); b[5] = (short)f2bf(vi[2]);
        b[6] = (short)f2bf(vr[3]); b[7] = (short)f2bf(vi[3]);
        bf16x8 af0 = *(const bf16x8*)(a0 + st * 32);
        bf16x8 af1 = *(const bf16x8*)(a1 + st * 32);
        acc0 = __builtin_amdgcn_mfma_f32_16x16x32_bf16(af0, b, acc0, 0, 0, 0);
        acc1 = __builtin_amdgcn_mfma_f32_16x16x32_bf16(af1, b, acc1, 0, 0, 0);
    }

    float* pp = part + (size_t)blk * 2048;
#pragma unroll
    for (int j = 0; j < 4; ++j) {
        pp[(4 * g + j) * 64 + o]      = acc0[j];
        pp[(16 + 4 * g + j) * 64 + o] = acc1[j];
    }
}

__global__ void fno_reduce(const float* __restrict__ part, float* __restrict__ out) {
    int idx = blockIdx.x * 256 + threadIdx.x;   // idx = b*64 + o
    float s0 = 0.f, s1 = 0.f, s2 = 0.f, s3 = 0.f;
    for (int j = 0; j < 1056; j += 4) {
        s0 += part[(size_t)j * 2048 + idx];
        s1 += part[(size_t)(j + 1) * 2048 + idx];
        s2 += part[(size_t)(j + 2) * 2048 + idx];
        s3 += part[(size_t)(j + 3) * 2048 + idx];
    }
    out[idx] = (s0 + s1) + (s2 + s3);
}

// ---------------------------------------------------------------------------
extern "C" void kernel_launch(void* const* d_in, const int* in_sizes, int n_in,
                              void* d_out, int out_size, void* d_ws, size_t ws_size,
                              hipStream_t stream) {
    const float* x  = (const float*)d_in[0];
    const float* wr = (const float*)d_in[1];
    const float* wi = (const float*)d_in[2];
    float* out = (float*)d_out;
    char* ws   = (char*)d_ws;

    ushort* T1f = (ushort*)(ws + OB_T1F);
    ushort* A2f = (ushort*)(ws + OB_A2F);
    ushort* Y   = (ushort*)(ws + OB_Y);
    ushort* XTb = (ushort*)(ws + OB_XTB);
    float* part = (float*)(ws + OB_PART);

    fno_tw<<<128, 256, 0, stream>>>(T1f, A2f);
    fno_gemm1<<<512, 256, 0, stream>>>(x, T1f, Y);
    fno_gemm2<<<1024, 256, 0, stream>>>(Y, A2f, XTb);
    fno_gemm3<<<1056, 256, 0, stream>>>(XTb, wr, wi, part);
    fno_reduce<<<8, 256, 0, stream>>>(part, out);
}

// Round 5
// 121.604 us; speedup vs baseline: 1.6172x; 1.6172x over previous
//
#include <hip/hip_runtime.h>
#include <math.h>

#define BATCH 32
#define CIn   32
#define COut  64
#define MODES 2112

typedef __attribute__((ext_vector_type(8))) short bf16x8;
typedef __attribute__((ext_vector_type(4))) float f32x4;

// ws byte offsets
#define OB_T1F  0u           // 20480 ushort
#define OB_A2F  40960u       // 32768 ushort
#define OB_Y    106496u      // 262144*66*2 = 34603008 B
#define OB_XTB  34709504u    // 1024*4224*2 = 8650752 B   [b][i][m][reim] bf16, signs folded
#define OB_PART 43360256u    // 384*2048*4 = 3145728 B

__device__ __forceinline__ ushort f2bf(float f) {
    union { float f; uint u; } v; v.f = f;
    uint r = (v.u + 0x7FFFu + ((v.u >> 16) & 1u)) >> 16;
    return (ushort)r;
}

__device__ __forceinline__ bf16x8 cvt8(f32x4 lo, f32x4 hi) {
    bf16x8 r;
    r[0] = (short)f2bf(lo[0]); r[1] = (short)f2bf(lo[1]);
    r[2] = (short)f2bf(lo[2]); r[3] = (short)f2bf(lo[3]);
    r[4] = (short)f2bf(hi[0]); r[5] = (short)f2bf(hi[1]);
    r[6] = (short)f2bf(hi[2]); r[7] = (short)f2bf(hi[3]);
    return r;
}

#define NB0 0
#define NB1 16
#define NB2 32
#define NB3 48
#define NB4 50

// ---------------------------------------------------------------------------
// Twiddle tables in MFMA-fragment-linear layout (unchanged).
// ---------------------------------------------------------------------------
__global__ void fno_tw(ushort* __restrict__ T1f, ushort* __restrict__ A2f) {
    const int nb[5] = {NB0, NB1, NB2, NB3, NB4};
    int idx = blockIdx.x * 256 + threadIdx.x;
    const float w0 = 6.28318530717958647692f / 256.0f;
    if (idx < 20480) {
        int i = idx & 7, l = (idx >> 3) & 63, ct = idx >> 9;
        int c = ct / 5, t = ct - 5 * c;
        int k = 32 * c + 8 * (l >> 4) + i;
        int n = nb[t] + (l & 15);
        int ky = n >> 1, s = n & 1;
        int m = (k * ky) & 255;
        float v = s ? -sinf(w0 * (float)m) : cosf(w0 * (float)m);
        T1f[idx] = f2bf(v * (1.0f / 65536.0f));
    }
    if (idx < 32768) {
        int i = idx & 7, l = (idx >> 3) & 63, cm = idx >> 9;
        int c = cm >> 2, mt = cm & 3;
        int kk = 32 * c + 8 * (l >> 4) + i;
        int kx = mt * 16 + (l & 15);
        int x = kk >> 1, s = kk & 1;
        int kxa = (kx < 32) ? kx : kx + 192;
        int m = (x * kxa) & 255;
        float v = s ? -sinf(w0 * (float)m) : cosf(w0 * (float)m);
        A2f[idx] = f2bf(v);
    }
}

// ---------------------------------------------------------------------------
// K1: Y = X @ T1. Barrier-FREE wave-local pipeline: each wave stages and
// reads only its own 16 LDS rows -> no cross-wave dependency. 3 rotating
// 16KB buffers, counted s_waitcnt vmcnt(8) (2 chunks in flight per wave).
// ---------------------------------------------------------------------------
#define MFMA5(CG, AV)                                                              \
    acc0 = __builtin_amdgcn_mfma_f32_16x16x32_bf16((AV), bfr[(CG)*5+0], acc0, 0,0,0); \
    acc1 = __builtin_amdgcn_mfma_f32_16x16x32_bf16((AV), bfr[(CG)*5+1], acc1, 0,0,0); \
    acc2 = __builtin_amdgcn_mfma_f32_16x16x32_bf16((AV), bfr[(CG)*5+2], acc2, 0,0,0); \
    acc3 = __builtin_amdgcn_mfma_f32_16x16x32_bf16((AV), bfr[(CG)*5+3], acc3, 0,0,0); \
    acc4 = __builtin_amdgcn_mfma_f32_16x16x32_bf16((AV), bfr[(CG)*5+4], acc4, 0,0,0);

// stage chunk CG (64 rows x 64 cols fp32) into buffer smx[CG%3]; wave w loads
// only its rows [16w,16w+16). LDS linear dest; source column pre-swizzled.
#define STAGE_CG(CG) do {                                                          \
    int cg_ = (CG);                                                                \
    size_t row0_ = (size_t)blk * 512 + (size_t)(cg_ >> 2) * 64;                    \
    int cc_ = cg_ & 3;                                                             \
    float* buf_ = &smx[cg_ % 3][0];                                                \
    _Pragma("unroll")                                                              \
    for (int j = 0; j < 4; ++j) {                                                  \
        int rr_ = ((w * 4 + j) << 2) + (lane >> 4);                                \
        int sg_ = (lane & 15) ^ (rr_ & 7);                                         \
        const float* gp_ = x + (row0_ + rr_) * 256 + cc_ * 64 + (sg_ << 2);        \
        char* lp_ = (char*)buf_ + ((w * 4 + j) << 10);                             \
        __builtin_amdgcn_global_load_lds(                                          \
            (const __attribute__((address_space(1))) unsigned int*)gp_,            \
            (__attribute__((address_space(3))) unsigned int*)lp_, 16, 0, 0);       \
    } } while (0)

#define WAITV(N) do {                                                              \
    asm volatile("s_waitcnt vmcnt(" #N ")" ::: "memory");                          \
    __builtin_amdgcn_sched_barrier(0); } while (0)

__global__ __launch_bounds__(256, 2)
void fno_gemm1(const float* __restrict__ x, const ushort* __restrict__ T1f,
               ushort* __restrict__ Y) {
    __shared__ float smx[3][4096];   // 3 x 16KB rotating chunk buffers
    const int tid  = threadIdx.x;
    const int lane = tid & 63;
    const int w    = tid >> 6;
    const int r0   = lane & 15;
    const int g    = lane >> 4;
    const int blk  = blockIdx.x;

    bf16x8 bfr[40];
    const bf16x8* bp = (const bf16x8*)T1f;
#pragma unroll
    for (int q = 0; q < 40; ++q) bfr[q] = bp[q * 64 + lane];

    const int rr = (w << 4) + r0;     // this wave's A-read row within chunk
    const int xr = rr & 7;

    STAGE_CG(0);
    STAGE_CG(1);

    for (int sl = 0; sl < 8; ++sl) {
        f32x4 acc0 = {0,0,0,0}, acc1 = {0,0,0,0}, acc2 = {0,0,0,0},
              acc3 = {0,0,0,0}, acc4 = {0,0,0,0};
#pragma unroll
        for (int c = 0; c < 4; ++c) {
            const int cg = sl * 4 + c;
            if (cg + 2 < 32) STAGE_CG(cg + 2);
            if (cg <= 29)      { WAITV(8); }
            else if (cg == 30) { WAITV(4); }
            else               { WAITV(0); }

            const float* rowp = &smx[cg % 3][rr * 64];
#pragma unroll
            for (int cl = 0; cl < 2; ++cl) {
                int s0 = (cl << 3) + (g << 1);
                f32x4 lo = *(const f32x4*)&rowp[((s0) ^ xr) << 2];
                f32x4 hi = *(const f32x4*)&rowp[((s0 + 1) ^ xr) << 2];
                bf16x8 a = cvt8(lo, hi);
                if (cl == 0) { MFMA5(2 * c + 0, a); }
                else         { MFMA5(2 * c + 1, a); }
            }
        }
        // strip complete: store Y for m-tile (sl*4 + w)
        size_t mtg = ((size_t)blk * 8 + sl) * 4 + w;
        ushort* yp = Y + mtg * (16 * 66);
#pragma unroll
        for (int j = 0; j < 4; ++j) {
            int row = 4 * g + j;
            yp[row * 66 + NB0 + r0] = f2bf(acc0[j]);
            yp[row * 66 + NB1 + r0] = f2bf(acc1[j]);
            yp[row * 66 + NB2 + r0] = f2bf(acc2[j]);
            yp[row * 66 + NB3 + r0] = f2bf(acc3[j]);
            if (r0 >= 14) yp[row * 66 + NB4 + r0] = f2bf(acc4[j]);
        }
    }
}

// ---------------------------------------------------------------------------
// K2: per plane XT[64,66] = A2 @ B2 (unchanged from round 4).
// ---------------------------------------------------------------------------
__global__ __launch_bounds__(256)
void fno_gemm2(const ushort* __restrict__ Y, const ushort* __restrict__ A2f,
               ushort* __restrict__ XTb) {
    __shared__ ushort B2t[66 * 512];
    const int tid = threadIdx.x;
    const int p   = blockIdx.x;

    const ushort* yp = Y + (size_t)p * (256 * 66);
    uint* b32 = (uint*)B2t;
    for (int e = tid; e < 8448; e += 256) {
        int xx = e / 33;
        int ky = e - 33 * xx;
        uint v = *(const uint*)(yp + xx * 66 + 2 * ky);
        uint yr = v & 0xffffu, yi = v >> 16;
        uint w0 = yr | ((yi ^ 0x8000u) << 16);
        uint w1 = yi | (yr << 16);
        int u = xx >> 2, off = xx & 3;
        int ra = 2 * ky, rb = 2 * ky + 1;
        b32[ra * 256 + ((u ^ (ra & 7)) << 2) + off] = w0;
        b32[rb * 256 + ((u ^ (rb & 7)) << 2) + off] = w1;
    }

    const int lane = tid & 63;
    const int mt   = tid >> 6;
    const int r0   = lane & 15;
    const int g    = lane >> 4;

    bf16x8 af[16];
    const bf16x8* ap = (const bf16x8*)A2f;
#pragma unroll
    for (int c = 0; c < 16; ++c) af[c] = ap[(c * 4 + mt) * 64 + lane];

    __syncthreads();

    const int nb[5] = {NB0, NB1, NB2, NB3, NB4};
    f32x4 acc[5];
#pragma unroll
    for (int t = 0; t < 5; ++t) acc[t] = (f32x4){0, 0, 0, 0};

#pragma unroll
    for (int c = 0; c < 16; ++c) {
#pragma unroll
        for (int t = 0; t < 5; ++t) {
            int row = nb[t] + r0;
            int u = (c << 2) + g;
            bf16x8 b = *(const bf16x8*)&B2t[row * 512 + ((u ^ (row & 7)) << 3)];
            acc[t] = __builtin_amdgcn_mfma_f32_16x16x32_bf16(af[c], b, acc[t], 0, 0, 0);
        }
    }

    __syncthreads();
    ushort* xtl = B2t;
#pragma unroll
    for (int t = 0; t < 5; ++t) {
        int n  = nb[t] + r0;
        int ky = n >> 1, im = n & 1;
#pragma unroll
        for (int j = 0; j < 4; ++j) {
            if (t == 4 && r0 < 14) continue;
            int kx = mt * 16 + 4 * g + j;
            float wgt = (kx < 32) ? ((kx == 0 && ky == 0) ? 1.f : 2.f)
                                  : ((ky == 0) ? 0.f : 2.f);
            if (im) wgt = -wgt;
            xtl[kx * 66 + 2 * ky + im] = f2bf(wgt * acc[t][j]);
        }
    }
    __syncthreads();

    const uint4* srcq = (const uint4*)xtl;
    uint4* dstq = (uint4*)(XTb + (size_t)p * 4224);
    for (int e = tid; e < 528; e += 256) dstq[e] = srcq[e];
}

// ---------------------------------------------------------------------------
// K3: out = XTb @ W. Split-K: 384 blocks = (ic 0..31, sc 0..11), K=352/block
// (11 MFMA steps). W fp32 read in fragment order, converted in-register.
// ---------------------------------------------------------------------------
__global__ __launch_bounds__(256)
void fno_gemm3(const ushort* __restrict__ XTb, const float* __restrict__ Wr,
               const float* __restrict__ Wi, float* __restrict__ part) {
    const int blk = blockIdx.x;
    const int ic  = blk / 12;
    const int sc  = blk - ic * 12;
    const int tid = threadIdx.x;
    const int lane = tid & 63;
    const int w    = tid >> 6;
    const int r0   = lane & 15;
    const int g    = lane >> 4;
    const int o    = (w << 4) + r0;

    const float* wrp = Wr + ((size_t)ic * 64 + o) * 2112 + sc * 176 + 4 * g;
    const float* wip = Wi + ((size_t)ic * 64 + o) * 2112 + sc * 176 + 4 * g;
    const ushort* a0 = XTb + ((size_t)r0 * 32 + ic) * 4224 + sc * 352 + 8 * g;
    const ushort* a1 = a0 + (size_t)16 * 32 * 4224;

    f32x4 acc0 = {0,0,0,0}, acc1 = {0,0,0,0};
#pragma unroll
    for (int st = 0; st < 11; ++st) {
        f32x4 vr = *(const f32x4*)(wrp + st * 16);
        f32x4 vi = *(const f32x4*)(wip + st * 16);
        bf16x8 b;
        b[0] = (short)f2bf(vr[0]); b[1] = (short)f2bf(vi[0]);
        b[2] = (short)f2bf(vr[1]); b[3] = (short)f2bf(vi[1]);
        b[4] = (short)f2bf(vr[2]); b[5] = (short)f2bf(vi[2]);
        b[6] = (short)f2bf(vr[3]); b[7] = (short)f2bf(vi[3]);
        bf16x8 af0 = *(const bf16x8*)(a0 + st * 32);
        bf16x8 af1 = *(const bf16x8*)(a1 + st * 32);
        acc0 = __builtin_amdgcn_mfma_f32_16x16x32_bf16(af0, b, acc0, 0, 0, 0);
        acc1 = __builtin_amdgcn_mfma_f32_16x16x32_bf16(af1, b, acc1, 0, 0, 0);
    }

    float* pp = part + (size_t)blk * 2048;
#pragma unroll
    for (int j = 0; j < 4; ++j) {
        pp[(4 * g + j) * 64 + o]      = acc0[j];
        pp[(16 + 4 * g + j) * 64 + o] = acc1[j];
    }
}

// ---------------------------------------------------------------------------
// Parallel reduce: 64 blocks x 256 thr; block owns 32 outputs, 8-way j-split.
// ---------------------------------------------------------------------------
__global__ __launch_bounds__(256)
void fno_reduce(const float* __restrict__ part, float* __restrict__ out) {
    __shared__ float red[8][32];
    const int tid = threadIdx.x;
    const int il  = tid & 31;
    const int js  = tid >> 5;
    const int idx = blockIdx.x * 32 + il;

    float s = 0.f;
#pragma unroll 4
    for (int t = 0; t < 48; ++t)
        s += part[(size_t)(js + 8 * t) * 2048 + idx];
    red[js][il] = s;
    __syncthreads();

    if (tid < 32) {
        float v = red[0][tid] + red[1][tid] + red[2][tid] + red[3][tid]
                + red[4][tid] + red[5][tid] + red[6][tid] + red[7][tid];
        out[blockIdx.x * 32 + tid] = v;
    }
}

// ---------------------------------------------------------------------------
extern "C" void kernel_launch(void* const* d_in, const int* in_sizes, int n_in,
                              void* d_out, int out_size, void* d_ws, size_t ws_size,
                              hipStream_t stream) {
    const float* x  = (const float*)d_in[0];
    const float* wr = (const float*)d_in[1];
    const float* wi = (const float*)d_in[2];
    float* out = (float*)d_out;
    char* ws   = (char*)d_ws;

    ushort* T1f = (ushort*)(ws + OB_T1F);
    ushort* A2f = (ushort*)(ws + OB_A2F);
    ushort* Y   = (ushort*)(ws + OB_Y);
    ushort* XTb = (ushort*)(ws + OB_XTB);
    float* part = (float*)(ws + OB_PART);

    fno_tw<<<128, 256, 0, stream>>>(T1f, A2f);
    fno_gemm1<<<512, 256, 0, stream>>>(x, T1f, Y);
    fno_gemm2<<<1024, 256, 0, stream>>>(Y, A2f, XTb);
    fno_gemm3<<<384, 256, 0, stream>>>(XTb, wr, wi, part);
    fno_reduce<<<64, 256, 0, stream>>>(part, out);
}

// Round 6
// 85.034 us; speedup vs baseline: 2.3128x; 1.4301x over previous
//
#include <hip/hip_runtime.h>
#include <math.h>

#define BATCH 32
#define CIn   32
#define COut  64

typedef __attribute__((ext_vector_type(8))) short bf16x8;
typedef __attribute__((ext_vector_type(4))) float f32x4;

// ws byte offsets
#define OB_T1F  0u           // 20480 ushort
#define OB_ECF  40960u       // 16384 ushort
#define OB_ESF  73728u       // 16384 ushort
#define OB_XTB  106496u      // 1024*4224*2 = 8650752 B  [b][i][kx*66+n] bf16, signs folded
#define OB_PART 8757248u     // 704*2048*4 = 5767168 B

__device__ __forceinline__ ushort f2bf(float f) {
    union { float f; uint u; } v; v.f = f;
    uint r = (v.u + 0x7FFFu + ((v.u >> 16) & 1u)) >> 16;
    return (ushort)r;
}

__device__ __forceinline__ bf16x8 cvt8(f32x4 lo, f32x4 hi) {
    bf16x8 r;
    r[0] = (short)f2bf(lo[0]); r[1] = (short)f2bf(lo[1]);
    r[2] = (short)f2bf(lo[2]); r[3] = (short)f2bf(lo[3]);
    r[4] = (short)f2bf(hi[0]); r[5] = (short)f2bf(hi[1]);
    r[6] = (short)f2bf(hi[2]); r[7] = (short)f2bf(hi[3]);
    return r;
}

#define NB0 0
#define NB1 16
#define NB2 32
#define NB3 48
#define NB4 50

// ---------------------------------------------------------------------------
// Twiddles. T1f: y-DFT B-frags (K=256 complex-interleaved cols, scaled 1/65536).
// Ecf/Esf: x-DFT A-frags, K=256 over x (real): cos / -sin of 2*pi*kxa*x/256.
// ---------------------------------------------------------------------------
__global__ void fno_tw(ushort* __restrict__ T1f, ushort* __restrict__ Ecf,
                       ushort* __restrict__ Esf) {
    const int nb[5] = {NB0, NB1, NB2, NB3, NB4};
    int idx = blockIdx.x * 256 + threadIdx.x;
    const float w0 = 6.28318530717958647692f / 256.0f;
    if (idx < 20480) {
        int i = idx & 7, l = (idx >> 3) & 63, ct = idx >> 9;
        int c = ct / 5, t = ct - 5 * c;
        int k = 32 * c + 8 * (l >> 4) + i;
        int n = nb[t] + (l & 15);
        int ky = n >> 1, s = n & 1;
        int m = (k * ky) & 255;
        float v = s ? -sinf(w0 * (float)m) : cosf(w0 * (float)m);
        T1f[idx] = f2bf(v * (1.0f / 65536.0f));
    }
    if (idx < 16384) {
        int i = idx & 7, l = (idx >> 3) & 63, km = idx >> 9;  // km = ks*4+mt
        int ks = km >> 2, mt = km & 3;
        int xx = ks * 32 + ((l >> 4) << 3) + i;
        int kx = mt * 16 + (l & 15);
        int kxa = (kx < 32) ? kx : kx + 192;
        int m = (xx * kxa) & 255;
        Ecf[idx] = f2bf(cosf(w0 * (float)m));
        Esf[idx] = f2bf(-sinf(w0 * (float)m));
    }
}

// ---------------------------------------------------------------------------
// Fused y-DFT + x-DFT. One block per plane (1024 blocks, 256 thr).
// Phase A: barrier-free wave-local async pipeline (2 x 16KB staging bufs,
//   counted vmcnt; no global stores in the loop -> no store stalls).
//   Row spectrum written to unit-swizzled LDS Yt[66][256] (lgkm, not vmcnt).
// Phase B: XT = (Ec + i*Es) . Yt via two real MFMA GEMMs K=256;
//   re/im recombined with shfl_xor(1); weights folded; coalesced store.
// ---------------------------------------------------------------------------
#define MFMA5(CG, AV)                                                              \
    acc0 = __builtin_amdgcn_mfma_f32_16x16x32_bf16((AV), bfr[(CG)*5+0], acc0, 0,0,0); \
    acc1 = __builtin_amdgcn_mfma_f32_16x16x32_bf16((AV), bfr[(CG)*5+1], acc1, 0,0,0); \
    acc2 = __builtin_amdgcn_mfma_f32_16x16x32_bf16((AV), bfr[(CG)*5+2], acc2, 0,0,0); \
    acc3 = __builtin_amdgcn_mfma_f32_16x16x32_bf16((AV), bfr[(CG)*5+3], acc3, 0,0,0); \
    acc4 = __builtin_amdgcn_mfma_f32_16x16x32_bf16((AV), bfr[(CG)*5+4], acc4, 0,0,0);

// stage chunk CG (64 rows x 64 cols fp32 = 16KB) into smx[CG&1]; wave w loads
// only its own rows [16w,16w+16). Linear LDS dest; source col pre-swizzled.
#define STAGE_CG(CG) do {                                                          \
    int cg_ = (CG);                                                                \
    const float* base_ = x + ((size_t)p * 256 + (size_t)(cg_ >> 2) * 64) * 256     \
                           + (cg_ & 3) * 64;                                       \
    float* buf_ = &smx[cg_ & 1][0];                                                \
    _Pragma("unroll")                                                              \
    for (int j = 0; j < 4; ++j) {                                                  \
        int rr_ = ((w * 4 + j) << 2) + (lane >> 4);                                \
        int sg_ = (lane & 15) ^ (rr_ & 7);                                         \
        const float* gp_ = base_ + (size_t)rr_ * 256 + (sg_ << 2);                 \
        char* lp_ = (char*)buf_ + ((w * 4 + j) << 10);                             \
        __builtin_amdgcn_global_load_lds(                                          \
            (const __attribute__((address_space(1))) unsigned int*)gp_,            \
            (__attribute__((address_space(3))) unsigned int*)lp_, 16, 0, 0);       \
    } } while (0)

#define WAITV(N) do {                                                              \
    asm volatile("s_waitcnt vmcnt(" #N ")" ::: "memory");                          \
    __builtin_amdgcn_sched_barrier(0); } while (0)

#define WAITL0 do {                                                                \
    asm volatile("s_waitcnt lgkmcnt(0)" ::: "memory");                             \
    __builtin_amdgcn_sched_barrier(0); } while (0)

// Yt write for one acc tile: n = nb[T]+r0, x-row = sl*64 + w*16 + 4g + j
#define YTW(ACC, T) do {                                                           \
    int n_ = nb[T] + r0;                                                           \
    if ((T) != 4 || r0 >= 14) {                                                    \
        _Pragma("unroll")                                                          \
        for (int j = 0; j < 4; ++j) {                                              \
            int xrow_ = sl * 64 + w * 16 + 4 * g + j;                              \
            int us_ = n_ * 256 + ((((xrow_ >> 3) ^ (n_ & 31)) << 3) | (xrow_ & 7));\
            Yt[us_] = f2bf((ACC)[j]);                                              \
        } } } while (0)

__global__ __launch_bounds__(256, 2)
void fno_fused(const float* __restrict__ x, const ushort* __restrict__ T1f,
               const ushort* __restrict__ Ecf, const ushort* __restrict__ Esf,
               ushort* __restrict__ XTb) {
    __shared__ float smx[2][4096];                 // 32 KB staging
    __shared__ __align__(16) ushort Yt[16896];     // 33.8 KB, unit-swizzled [66][256]
    const int nb[5] = {NB0, NB1, NB2, NB3, NB4};
    const int tid  = threadIdx.x;
    const int lane = tid & 63;
    const int w    = tid >> 6;
    const int r0   = lane & 15;
    const int g    = lane >> 4;
    const int p    = blockIdx.x;                   // plane = b*CIn + i

    bf16x8 bfr[40];
    const bf16x8* bp = (const bf16x8*)T1f;
#pragma unroll
    for (int q = 0; q < 40; ++q) bfr[q] = bp[q * 64 + lane];

    const int rr = (w << 4) + r0;
    const int xr = rr & 7;

    STAGE_CG(0);
    STAGE_CG(1);

    f32x4 acc0, acc1, acc2, acc3, acc4;
#pragma unroll
    for (int cg = 0; cg < 16; ++cg) {
        if ((cg & 3) == 0) {
            acc0 = (f32x4){0,0,0,0}; acc1 = (f32x4){0,0,0,0};
            acc2 = (f32x4){0,0,0,0}; acc3 = (f32x4){0,0,0,0};
            acc4 = (f32x4){0,0,0,0};
        }
        if (cg < 15) { WAITV(4); } else { WAITV(0); }

        const float* rowp = &smx[cg & 1][rr * 64];
        f32x4 lo0 = *(const f32x4*)&rowp[(((g << 1)    ) ^ xr) << 2];
        f32x4 hi0 = *(const f32x4*)&rowp[(((g << 1) + 1) ^ xr) << 2];
        f32x4 lo1 = *(const f32x4*)&rowp[((8 + (g << 1)    ) ^ xr) << 2];
        f32x4 hi1 = *(const f32x4*)&rowp[((8 + (g << 1) + 1) ^ xr) << 2];
        WAITL0;                         // reads done before overwriting buffer
        if (cg + 2 < 16) STAGE_CG(cg + 2);

        bf16x8 a0v = cvt8(lo0, hi0);
        bf16x8 a1v = cvt8(lo1, hi1);
        MFMA5(2 * (cg & 3)    , a0v);
        MFMA5(2 * (cg & 3) + 1, a1v);

        if ((cg & 3) == 3) {            // strip complete -> Yt (LDS only)
            int sl = cg >> 2;
            YTW(acc0, 0); YTW(acc1, 1); YTW(acc2, 2); YTW(acc3, 3); YTW(acc4, 4);
        }
    }
    __syncthreads();

    // ---- Phase B: P1 = Ec . Yt, P2 = Es . Yt  (M=64 kx, N=66, K=256 x) ----
    const int mt = w;
    f32x4 P1[5], P2[5];
#pragma unroll
    for (int t = 0; t < 5; ++t) { P1[t] = (f32x4){0,0,0,0}; P2[t] = (f32x4){0,0,0,0}; }

    const bf16x8* ecp = (const bf16x8*)Ecf;
    const bf16x8* esp = (const bf16x8*)Esf;
#pragma unroll
    for (int ks = 0; ks < 8; ++ks) {
        bf16x8 ea = ecp[(ks * 4 + mt) * 64 + lane];
        bf16x8 es = esp[(ks * 4 + mt) * 64 + lane];
#pragma unroll
        for (int t = 0; t < 5; ++t) {
            int n = nb[t] + r0;
            bf16x8 b = *(const bf16x8*)&Yt[n * 256 + ((((ks << 2) + g) ^ (n & 31)) << 3)];
            P1[t] = __builtin_amdgcn_mfma_f32_16x16x32_bf16(ea, b, P1[t], 0, 0, 0);
            P2[t] = __builtin_amdgcn_mfma_f32_16x16x32_bf16(es, b, P2[t], 0, 0, 0);
        }
    }

    // recombine re/im across lane pairs, fold weights, stage in LDS, store
    ushort* xtl = (ushort*)&smx[0][0];   // 4224 ushort, smx free after phase A
#pragma unroll
    for (int t = 0; t < 5; ++t) {
        int n  = nb[t] + r0;
        int ky = n >> 1, im = n & 1;
#pragma unroll
        for (int j = 0; j < 4; ++j) {
            float v2x = __shfl_xor(P2[t][j], 1);
            if (t == 4 && r0 < 14) continue;
            int kx = mt * 16 + 4 * g + j;
            float val = im ? (P1[t][j] + v2x) : (P1[t][j] - v2x);
            float wgt = (kx < 32) ? ((kx == 0 && ky == 0) ? 1.f : 2.f)
                                  : ((ky == 0) ? 0.f : 2.f);
            if (im) wgt = -wgt;          // fold the (-XTi)*Wi sign
            xtl[kx * 66 + n] = f2bf(wgt * val);
        }
    }
    __syncthreads();

    const uint4* srcq = (const uint4*)xtl;
    uint4* dstq = (uint4*)(XTb + (size_t)p * 4224);
    for (int e = tid; e < 528; e += 256) dstq[e] = srcq[e];
}

// ---------------------------------------------------------------------------
// K3: out = XTb @ W. Split-K: 704 blocks = (ic 0..31, sc 0..21), K=192
// (6 MFMA steps). W fp32 read in fragment order, converted in-register.
// ---------------------------------------------------------------------------
__global__ __launch_bounds__(256)
void fno_gemm3(const ushort* __restrict__ XTb, const float* __restrict__ Wr,
               const float* __restrict__ Wi, float* __restrict__ part) {
    const int blk = blockIdx.x;
    const int ic  = blk / 22;
    const int sc  = blk - ic * 22;
    const int tid = threadIdx.x;
    const int lane = tid & 63;
    const int w    = tid >> 6;
    const int r0   = lane & 15;
    const int g    = lane >> 4;
    const int o    = (w << 4) + r0;

    const float* wrp = Wr + ((size_t)ic * 64 + o) * 2112 + sc * 96 + 4 * g;
    const float* wip = Wi + ((size_t)ic * 64 + o) * 2112 + sc * 96 + 4 * g;
    const ushort* a0 = XTb + ((size_t)r0 * 32 + ic) * 4224 + sc * 192 + 8 * g;
    const ushort* a1 = a0 + (size_t)16 * 32 * 4224;

    f32x4 acc0 = {0,0,0,0}, acc1 = {0,0,0,0};
#pragma unroll
    for (int st = 0; st < 6; ++st) {
        f32x4 vr = *(const f32x4*)(wrp + st * 16);
        f32x4 vi = *(const f32x4*)(wip + st * 16);
        bf16x8 b;
        b[0] = (short)f2bf(vr[0]); b[1] = (short)f2bf(vi[0]);
        b[2] = (short)f2bf(vr[1]); b[3] = (short)f2bf(vi[1]);
        b[4] = (short)f2bf(vr[2]); b[5] = (short)f2bf(vi[2]);
        b[6] = (short)f2bf(vr[3]); b[7] = (short)f2bf(vi[3]);
        bf16x8 af0 = *(const bf16x8*)(a0 + st * 32);
        bf16x8 af1 = *(const bf16x8*)(a1 + st * 32);
        acc0 = __builtin_amdgcn_mfma_f32_16x16x32_bf16(af0, b, acc0, 0, 0, 0);
        acc1 = __builtin_amdgcn_mfma_f32_16x16x32_bf16(af1, b, acc1, 0, 0, 0);
    }

    float* pp = part + (size_t)blk * 2048;
#pragma unroll
    for (int j = 0; j < 4; ++j) {
        pp[(4 * g + j) * 64 + o]      = acc0[j];
        pp[(16 + 4 * g + j) * 64 + o] = acc1[j];
    }
}

// ---------------------------------------------------------------------------
// Parallel reduce: 64 blocks x 256 thr; block owns 32 outputs, 8-way j-split.
// ---------------------------------------------------------------------------
__global__ __launch_bounds__(256)
void fno_reduce(const float* __restrict__ part, float* __restrict__ out) {
    __shared__ float red[8][32];
    const int tid = threadIdx.x;
    const int il  = tid & 31;
    const int js  = tid >> 5;
    const int idx = blockIdx.x * 32 + il;

    float s = 0.f;
#pragma unroll 4
    for (int t = 0; t < 88; ++t)
        s += part[(size_t)(js + 8 * t) * 2048 + idx];
    red[js][il] = s;
    __syncthreads();

    if (tid < 32) {
        float v = red[0][tid] + red[1][tid] + red[2][tid] + red[3][tid]
                + red[4][tid] + red[5][tid] + red[6][tid] + red[7][tid];
        out[blockIdx.x * 32 + tid] = v;
    }
}

// ---------------------------------------------------------------------------
extern "C" void kernel_launch(void* const* d_in, const int* in_sizes, int n_in,
                              void* d_out, int out_size, void* d_ws, size_t ws_size,
                              hipStream_t stream) {
    const float* x  = (const float*)d_in[0];
    const float* wr = (const float*)d_in[1];
    const float* wi = (const float*)d_in[2];
    float* out = (float*)d_out;
    char* ws   = (char*)d_ws;

    ushort* T1f = (ushort*)(ws + OB_T1F);
    ushort* Ecf = (ushort*)(ws + OB_ECF);
    ushort* Esf = (ushort*)(ws + OB_ESF);
    ushort* XTb = (ushort*)(ws + OB_XTB);
    float* part = (float*)(ws + OB_PART);

    fno_tw<<<80, 256, 0, stream>>>(T1f, Ecf, Esf);
    fno_fused<<<1024, 256, 0, stream>>>(x, T1f, Ecf, Esf, XTb);
    fno_gemm3<<<704, 256, 0, stream>>>(XTb, wr, wi, part);
    fno_reduce<<<64, 256, 0, stream>>>(part, out);
}

// Round 7
// 80.302 us; speedup vs baseline: 2.4490x; 1.0589x over previous
//
#include <hip/hip_runtime.h>
#include <hip/hip_bf16.h>
#include <math.h>

#define BATCH 32
#define CIn   32
#define COut  64

typedef __attribute__((ext_vector_type(8))) short bf16x8;
typedef __attribute__((ext_vector_type(4))) float f32x4;

// ws byte offsets
#define OB_T1F  0u           // 20480 ushort
#define OB_ECF  40960u       // 16384 ushort
#define OB_ESF  73728u       // 16384 ushort
#define OB_XTB  106496u      // 1024*4224*2 = 8650752 B  [b][i][kx*66+n] bf16, signs folded
#define OB_PART 8757248u     // 704*2048*4 = 5767168 B

__device__ __forceinline__ ushort f2bf(float f) {
    union { float f; uint u; } v; v.f = f;
    uint r = (v.u + 0x7FFFu + ((v.u >> 16) & 1u)) >> 16;
    return (ushort)r;
}

// native converts (compiler emits v_cvt_pk_bf16_f32)
__device__ __forceinline__ ushort f2bfn(float f) {
    union { __hip_bfloat16 h; ushort u; } v;
    v.h = __float2bfloat16(f);
    return v.u;
}
__device__ __forceinline__ bf16x8 cvt8(f32x4 lo, f32x4 hi) {
    union { __hip_bfloat162 h2[4]; bf16x8 v; } u;
    u.h2[0] = __float22bfloat162_rn(make_float2(lo[0], lo[1]));
    u.h2[1] = __float22bfloat162_rn(make_float2(lo[2], lo[3]));
    u.h2[2] = __float22bfloat162_rn(make_float2(hi[0], hi[1]));
    u.h2[3] = __float22bfloat162_rn(make_float2(hi[2], hi[3]));
    return u.v;
}

#define NB0 0
#define NB1 16
#define NB2 32
#define NB3 48
#define NB4 50

// ---------------------------------------------------------------------------
// Twiddles (unchanged layout). T1f: y-DFT B-frags, scaled 1/65536.
// Ecf/Esf: x-DFT A-frags: cos / -sin of 2*pi*kxa*x/256.
// ---------------------------------------------------------------------------
__global__ void fno_tw(ushort* __restrict__ T1f, ushort* __restrict__ Ecf,
                       ushort* __restrict__ Esf) {
    const int nb[5] = {NB0, NB1, NB2, NB3, NB4};
    int idx = blockIdx.x * 256 + threadIdx.x;
    const float w0 = 6.28318530717958647692f / 256.0f;
    if (idx < 20480) {
        int i = idx & 7, l = (idx >> 3) & 63, ct = idx >> 9;
        int c = ct / 5, t = ct - 5 * c;
        int k = 32 * c + 8 * (l >> 4) + i;
        int n = nb[t] + (l & 15);
        int ky = n >> 1, s = n & 1;
        int m = (k * ky) & 255;
        float v = s ? -sinf(w0 * (float)m) : cosf(w0 * (float)m);
        T1f[idx] = f2bf(v * (1.0f / 65536.0f));
    }
    if (idx < 16384) {
        int i = idx & 7, l = (idx >> 3) & 63, km = idx >> 9;  // km = ks*4+mt
        int ks = km >> 2, mt = km & 3;
        int xx = ks * 32 + ((l >> 4) << 3) + i;
        int kx = mt * 16 + (l & 15);
        int kxa = (kx < 32) ? kx : kx + 192;
        int m = (xx * kxa) & 255;
        Ecf[idx] = f2bf(cosf(w0 * (float)m));
        Esf[idx] = f2bf(-sinf(w0 * (float)m));
    }
}

// ---------------------------------------------------------------------------
// Fused y-DFT + x-DFT, one block per plane. Phase A: wave-local, barrier-free,
// 32 chunks of (16 rows x 32 cols)/wave, 4 rotating LDS bufs, reg-level
// ds_read prefetch (lgkm latency hidden under MFMAs of previous chunk).
// ---------------------------------------------------------------------------
#define MFMA5(KC, AV)                                                              \
    acc0 = __builtin_amdgcn_mfma_f32_16x16x32_bf16((AV), bfr[(KC)*5+0], acc0, 0,0,0); \
    acc1 = __builtin_amdgcn_mfma_f32_16x16x32_bf16((AV), bfr[(KC)*5+1], acc1, 0,0,0); \
    acc2 = __builtin_amdgcn_mfma_f32_16x16x32_bf16((AV), bfr[(KC)*5+2], acc2, 0,0,0); \
    acc3 = __builtin_amdgcn_mfma_f32_16x16x32_bf16((AV), bfr[(KC)*5+3], acc3, 0,0,0); \
    acc4 = __builtin_amdgcn_mfma_f32_16x16x32_bf16((AV), bfr[(KC)*5+4], acc4, 0,0,0);

// stage chunk CG: wave w loads its 16 rows x 32 cols into smx[CG&3] (2 KB).
// Linear LDS dest; global source slot pre-swizzled (involution s^(r&7)).
#define STAGE_CG(CG) do {                                                          \
    int cg_ = (CG);                                                                \
    int sl_ = cg_ >> 3, kc_ = cg_ & 7;                                             \
    _Pragma("unroll")                                                              \
    for (int j = 0; j < 2; ++j) {                                                  \
        int rws_ = 8 * j + (lane >> 3);                                            \
        int sg_  = (lane & 7) ^ (rws_ & 7);                                        \
        const float* gp_ = x + ((size_t)p * 256 + sl_ * 64 + w * 16 + rws_) * 256  \
                             + kc_ * 32 + (sg_ << 2);                              \
        char* lp_ = (char*)&smx[cg_ & 3][0] + w * 2048 + j * 1024 + (lane << 4);   \
        __builtin_amdgcn_global_load_lds(                                          \
            (const __attribute__((address_space(1))) unsigned int*)gp_,            \
            (__attribute__((address_space(3))) unsigned int*)lp_, 16, 0, 0);       \
    } } while (0)

// ds_read chunk CG's A-frag halves into RA/RB (2 x b128, XOR-deswizzled)
#define DSR(CG, RA, RB) do {                                                       \
    const char* base_ = (const char*)&smx[(CG) & 3][0] + w * 2048 + r0 * 128;      \
    (RA) = *(const f32x4*)(base_ + ((((g << 1)    ) ^ xr) << 4));                  \
    (RB) = *(const f32x4*)(base_ + ((((g << 1) + 1) ^ xr) << 4));                  \
    } while (0)

#define WAITV(N) do {                                                              \
    asm volatile("s_waitcnt vmcnt(" #N ")" ::: "memory");                          \
    __builtin_amdgcn_sched_barrier(0); } while (0)

#define WAITL0 do {                                                                \
    asm volatile("s_waitcnt lgkmcnt(0)" ::: "memory");                             \
    __builtin_amdgcn_sched_barrier(0); } while (0)

// Yt write: n = nb[T]+r0, x-row = sl*64 + w*16 + 4g + j, unit-swizzled
#define YTW(ACC, T) do {                                                           \
    int n_ = nb[T] + r0;                                                           \
    if ((T) != 4 || r0 >= 14) {                                                    \
        _Pragma("unroll")                                                          \
        for (int j = 0; j < 4; ++j) {                                              \
            int xrow_ = sl * 64 + w * 16 + 4 * g + j;                              \
            int us_ = n_ * 256 + ((((xrow_ >> 3) ^ (n_ & 31)) << 3) | (xrow_ & 7));\
            Yt[us_] = f2bfn((ACC)[j]);                                             \
        } } } while (0)

__global__ __launch_bounds__(256, 2)
void fno_fused(const float* __restrict__ x, const ushort* __restrict__ T1f,
               const ushort* __restrict__ Ecf, const ushort* __restrict__ Esf,
               ushort* __restrict__ XTb) {
    __shared__ float smx[4][2048];                 // 4 x 8KB rotating staging
    __shared__ __align__(16) ushort Yt[16896];     // 33.8 KB unit-swizzled [66][256]
    const int nb[5] = {NB0, NB1, NB2, NB3, NB4};
    const int tid  = threadIdx.x;
    const int lane = tid & 63;
    const int w    = tid >> 6;
    const int r0   = lane & 15;
    const int g    = lane >> 4;
    const int xr   = r0 & 7;
    const int p    = blockIdx.x;                   // plane = b*CIn + i

    bf16x8 bfr[40];
    const bf16x8* bp = (const bf16x8*)T1f;
#pragma unroll
    for (int q = 0; q < 40; ++q) bfr[q] = bp[q * 64 + lane];

    f32x4 rA[2][2];                                // reg double-buffer (static idx)

    STAGE_CG(0); STAGE_CG(1); STAGE_CG(2);
    WAITV(4);                                      // chunk 0 staged
    DSR(0, rA[0][0], rA[0][1]);

    f32x4 acc0, acc1, acc2, acc3, acc4;
#pragma unroll
    for (int cg = 0; cg < 32; ++cg) {
        if ((cg & 7) == 0) {
            acc0 = (f32x4){0,0,0,0}; acc1 = (f32x4){0,0,0,0};
            acc2 = (f32x4){0,0,0,0}; acc3 = (f32x4){0,0,0,0};
            acc4 = (f32x4){0,0,0,0};
        }
        WAITL0;                                    // chunk cg's ds_reads done
        bf16x8 af = cvt8(rA[cg & 1][0], rA[cg & 1][1]);
        if (cg + 3 < 32) STAGE_CG(cg + 3);
        if (cg <= 28)      { WAITV(4); }           // chunk cg+1 staged, 2 in flight
        else if (cg == 29) { WAITV(2); }
        else if (cg == 30) { WAITV(0); }
        if (cg + 1 < 32) DSR(cg + 1, rA[(cg + 1) & 1][0], rA[(cg + 1) & 1][1]);
        MFMA5(cg & 7, af);
        if ((cg & 7) == 7) {                       // strip complete -> Yt (LDS)
            int sl = cg >> 3;
            YTW(acc0, 0); YTW(acc1, 1); YTW(acc2, 2); YTW(acc3, 3); YTW(acc4, 4);
        }
    }
    __syncthreads();

    // ---- Phase B: P1 = Ec . Yt, P2 = Es . Yt  (M=64 kx, N=66, K=256 x) ----
    const int mt = w;
    f32x4 P1[5], P2[5];
#pragma unroll
    for (int t = 0; t < 5; ++t) { P1[t] = (f32x4){0,0,0,0}; P2[t] = (f32x4){0,0,0,0}; }

    const bf16x8* ecp = (const bf16x8*)Ecf;
    const bf16x8* esp = (const bf16x8*)Esf;
#pragma unroll
    for (int ks = 0; ks < 8; ++ks) {
        bf16x8 ea = ecp[(ks * 4 + mt) * 64 + lane];
        bf16x8 es = esp[(ks * 4 + mt) * 64 + lane];
#pragma unroll
        for (int t = 0; t < 5; ++t) {
            int n = nb[t] + r0;
            bf16x8 b = *(const bf16x8*)&Yt[n * 256 + ((((ks << 2) + g) ^ (n & 31)) << 3)];
            P1[t] = __builtin_amdgcn_mfma_f32_16x16x32_bf16(ea, b, P1[t], 0, 0, 0);
            P2[t] = __builtin_amdgcn_mfma_f32_16x16x32_bf16(es, b, P2[t], 0, 0, 0);
        }
    }

    // recombine re/im across lane pairs, fold weights, stage in LDS, store
    ushort* xtl = (ushort*)&smx[0][0];             // 4224 ushort (spans smx)
#pragma unroll
    for (int t = 0; t < 5; ++t) {
        int n  = nb[t] + r0;
        int ky = n >> 1, im = n & 1;
#pragma unroll
        for (int j = 0; j < 4; ++j) {
            float v2x = __shfl_xor(P2[t][j], 1);
            if (t == 4 && r0 < 14) continue;
            int kx = mt * 16 + 4 * g + j;
            float val = im ? (P1[t][j] + v2x) : (P1[t][j] - v2x);
            float wgt = (kx < 32) ? ((kx == 0 && ky == 0) ? 1.f : 2.f)
                                  : ((ky == 0) ? 0.f : 2.f);
            if (im) wgt = -wgt;                    // fold the (-XTi)*Wi sign
            xtl[kx * 66 + n] = f2bfn(wgt * val);
        }
    }
    __syncthreads();

    const uint4* srcq = (const uint4*)xtl;
    uint4* dstq = (uint4*)(XTb + (size_t)p * 4224);
    for (int e = tid; e < 528; e += 256) dstq[e] = srcq[e];
}

// ---------------------------------------------------------------------------
// K3: out = XTb @ W. Split-K: 704 blocks = (ic 0..31, sc 0..21), K=192
// (6 MFMA steps). W fp32 in fragment order, packed-converted in-register.
// ---------------------------------------------------------------------------
__global__ __launch_bounds__(256)
void fno_gemm3(const ushort* __restrict__ XTb, const float* __restrict__ Wr,
               const float* __restrict__ Wi, float* __restrict__ part) {
    const int blk = blockIdx.x;
    const int ic  = blk / 22;
    const int sc  = blk - ic * 22;
    const int tid = threadIdx.x;
    const int lane = tid & 63;
    const int w    = tid >> 6;
    const int r0   = lane & 15;
    const int g    = lane >> 4;
    const int o    = (w << 4) + r0;

    const float* wrp = Wr + ((size_t)ic * 64 + o) * 2112 + sc * 96 + 4 * g;
    const float* wip = Wi + ((size_t)ic * 64 + o) * 2112 + sc * 96 + 4 * g;
    const ushort* a0 = XTb + ((size_t)r0 * 32 + ic) * 4224 + sc * 192 + 8 * g;
    const ushort* a1 = a0 + (size_t)16 * 32 * 4224;

    f32x4 acc0 = {0,0,0,0}, acc1 = {0,0,0,0};
#pragma unroll
    for (int st = 0; st < 6; ++st) {
        f32x4 vr = *(const f32x4*)(wrp + st * 16);
        f32x4 vi = *(const f32x4*)(wip + st * 16);
        union { __hip_bfloat162 h2[4]; bf16x8 v; } ub;
        ub.h2[0] = __float22bfloat162_rn(make_float2(vr[0], vi[0]));
        ub.h2[1] = __float22bfloat162_rn(make_float2(vr[1], vi[1]));
        ub.h2[2] = __float22bfloat162_rn(make_float2(vr[2], vi[2]));
        ub.h2[3] = __float22bfloat162_rn(make_float2(vr[3], vi[3]));
        bf16x8 af0 = *(const bf16x8*)(a0 + st * 32);
        bf16x8 af1 = *(const bf16x8*)(a1 + st * 32);
        acc0 = __builtin_amdgcn_mfma_f32_16x16x32_bf16(af0, ub.v, acc0, 0, 0, 0);
        acc1 = __builtin_amdgcn_mfma_f32_16x16x32_bf16(af1, ub.v, acc1, 0, 0, 0);
    }

    float* pp = part + (size_t)blk * 2048;
#pragma unroll
    for (int j = 0; j < 4; ++j) {
        pp[(4 * g + j) * 64 + o]      = acc0[j];
        pp[(16 + 4 * g + j) * 64 + o] = acc1[j];
    }
}

// ---------------------------------------------------------------------------
// Parallel reduce: 256 blocks x 256 thr; block owns 8 outputs, 32-way K-split.
// Fixed summation order -> deterministic.
// ---------------------------------------------------------------------------
__global__ __launch_bounds__(256)
void fno_reduce(const float* __restrict__ part, float* __restrict__ out) {
    __shared__ float red[256];
    const int tid = threadIdx.x;
    const int il  = tid & 7;
    const int js  = tid >> 3;                      // 0..31
    const int idx = blockIdx.x * 8 + il;

    float s = 0.f;
#pragma unroll
    for (int t = 0; t < 22; ++t)
        s += part[(size_t)(js + 32 * t) * 2048 + idx];
    red[tid] = s;
    __syncthreads();

    if (tid < 8) {
        float v = 0.f;
#pragma unroll
        for (int q = 0; q < 32; ++q) v += red[q * 8 + tid];
        out[blockIdx.x * 8 + tid] = v;
    }
}

// ---------------------------------------------------------------------------
extern "C" void kernel_launch(void* const* d_in, const int* in_sizes, int n_in,
                              void* d_out, int out_size, void* d_ws, size_t ws_size,
                              hipStream_t stream) {
    const float* x  = (const float*)d_in[0];
    const float* wr = (const float*)d_in[1];
    const float* wi = (const float*)d_in[2];
    float* out = (float*)d_out;
    char* ws   = (char*)d_ws;

    ushort* T1f = (ushort*)(ws + OB_T1F);
    ushort* Ecf = (ushort*)(ws + OB_ECF);
    ushort* Esf = (ushort*)(ws + OB_ESF);
    ushort* XTb = (ushort*)(ws + OB_XTB);
    float* part = (float*)(ws + OB_PART);

    fno_tw<<<80, 256, 0, stream>>>(T1f, Ecf, Esf);
    fno_fused<<<1024, 256, 0, stream>>>(x, T1f, Ecf, Esf, XTb);
    fno_gemm3<<<704, 256, 0, stream>>>(XTb, wr, wi, part);
    fno_reduce<<<256, 256, 0, stream>>>(part, out);
}

// Round 8
// 79.473 us; speedup vs baseline: 2.4746x; 1.0104x over previous
//
#include <hip/hip_runtime.h>
#include <hip/hip_bf16.h>
#include <math.h>

#define BATCH 32
#define CIn   32
#define COut  64

typedef __attribute__((ext_vector_type(8))) short bf16x8;
typedef __attribute__((ext_vector_type(4))) float f32x4;

// ws byte offsets
#define OB_T1F  0u           // 20480 ushort
#define OB_ECF  40960u       // 16384 ushort
#define OB_ESF  73728u       // 16384 ushort
#define OB_XTB  106496u      // 1024*4224*2 = 8650752 B  [b][i][kx*66+n] bf16, signs folded
#define OB_PART 8757248u     // 704*2048*4 = 5767168 B

__device__ __forceinline__ ushort f2bf(float f) {
    union { float f; uint u; } v; v.f = f;
    uint r = (v.u + 0x7FFFu + ((v.u >> 16) & 1u)) >> 16;
    return (ushort)r;
}

// native converts (compiler emits v_cvt_pk_bf16_f32)
__device__ __forceinline__ ushort f2bfn(float f) {
    union { __hip_bfloat16 h; ushort u; } v;
    v.h = __float2bfloat16(f);
    return v.u;
}
__device__ __forceinline__ bf16x8 cvt8(f32x4 lo, f32x4 hi) {
    union { __hip_bfloat162 h2[4]; bf16x8 v; } u;
    u.h2[0] = __float22bfloat162_rn(make_float2(lo[0], lo[1]));
    u.h2[1] = __float22bfloat162_rn(make_float2(lo[2], lo[3]));
    u.h2[2] = __float22bfloat162_rn(make_float2(hi[0], hi[1]));
    u.h2[3] = __float22bfloat162_rn(make_float2(hi[2], hi[3]));
    return u.v;
}

#define NB0 0
#define NB1 16
#define NB2 32
#define NB3 48
#define NB4 50

// ---------------------------------------------------------------------------
// Twiddles (unchanged). T1f: y-DFT B-frags, scaled 1/65536.
// Ecf/Esf: x-DFT A-frags: cos / -sin of 2*pi*kxa*x/256.
// ---------------------------------------------------------------------------
__global__ void fno_tw(ushort* __restrict__ T1f, ushort* __restrict__ Ecf,
                       ushort* __restrict__ Esf) {
    const int nb[5] = {NB0, NB1, NB2, NB3, NB4};
    int idx = blockIdx.x * 256 + threadIdx.x;
    const float w0 = 6.28318530717958647692f / 256.0f;
    if (idx < 20480) {
        int i = idx & 7, l = (idx >> 3) & 63, ct = idx >> 9;
        int c = ct / 5, t = ct - 5 * c;
        int k = 32 * c + 8 * (l >> 4) + i;
        int n = nb[t] + (l & 15);
        int ky = n >> 1, s = n & 1;
        int m = (k * ky) & 255;
        float v = s ? -sinf(w0 * (float)m) : cosf(w0 * (float)m);
        T1f[idx] = f2bf(v * (1.0f / 65536.0f));
    }
    if (idx < 16384) {
        int i = idx & 7, l = (idx >> 3) & 63, km = idx >> 9;  // km = ks*4+mt
        int ks = km >> 2, mt = km & 3;
        int xx = ks * 32 + ((l >> 4) << 3) + i;
        int kx = mt * 16 + (l & 15);
        int kxa = (kx < 32) ? kx : kx + 192;
        int m = (xx * kxa) & 255;
        Ecf[idx] = f2bf(cosf(w0 * (float)m));
        Esf[idx] = f2bf(-sinf(w0 * (float)m));
    }
}

// ---------------------------------------------------------------------------
// Fused y-DFT + x-DFT, one block per plane. Phase A: wave-local, barrier-free,
// 16 superchunks of (16 rows x 64 cols)/wave = 2 K-steps each; 2 rotating
// 16KB bufs; one lgkmcnt(0) + one vmcnt wait per 10 MFMAs.
// ---------------------------------------------------------------------------
#define MFMA5(KC, AV)                                                              \
    acc0 = __builtin_amdgcn_mfma_f32_16x16x32_bf16((AV), bfr[(KC)*5+0], acc0, 0,0,0); \
    acc1 = __builtin_amdgcn_mfma_f32_16x16x32_bf16((AV), bfr[(KC)*5+1], acc1, 0,0,0); \
    acc2 = __builtin_amdgcn_mfma_f32_16x16x32_bf16((AV), bfr[(KC)*5+2], acc2, 0,0,0); \
    acc3 = __builtin_amdgcn_mfma_f32_16x16x32_bf16((AV), bfr[(KC)*5+3], acc3, 0,0,0); \
    acc4 = __builtin_amdgcn_mfma_f32_16x16x32_bf16((AV), bfr[(KC)*5+4], acc4, 0,0,0);

// stage superchunk SC: wave w loads its 16 rows x 64 cols (4 KB) into
// smx[SC&1] + w*4096B via 4 global_load_lds (linear dest base + lane*16;
// source 16B-slot pre-swizzled with involution s ^ (row&7)).
#define STAGE_SC(SC) do {                                                          \
    int sc_ = (SC);                                                                \
    const float* gb_ = x + ((size_t)p * 256 + (sc_ >> 2) * 64 + w * 16) * 256      \
                         + (sc_ & 3) * 64;                                         \
    char* lb_ = (char*)&smx[sc_ & 1][0] + w * 4096;                                \
    _Pragma("unroll")                                                              \
    for (int j = 0; j < 4; ++j) {                                                  \
        int row_ = 4 * j + (lane >> 4);                                            \
        int sg_  = (lane & 15) ^ (row_ & 7);                                       \
        const float* gp_ = gb_ + (size_t)row_ * 256 + (sg_ << 2);                  \
        char* lp_ = lb_ + j * 1024;                                                \
        __builtin_amdgcn_global_load_lds(                                          \
            (const __attribute__((address_space(1))) unsigned int*)gp_,            \
            (__attribute__((address_space(3))) unsigned int*)lp_, 16, 0, 0);       \
    } } while (0)

// read both K-step A-frags of superchunk SC (4 x b128, XOR-deswizzled)
#define DSR4(SC) do {                                                              \
    const char* db_ = (const char*)&smx[(SC) & 1][0] + w * 4096 + r0 * 256;        \
    f32x4* rp_ = rr[(SC) & 1];                                                     \
    rp_[0] = *(const f32x4*)(db_ + (((((g << 1)    )) ^ xr) << 4));                \
    rp_[1] = *(const f32x4*)(db_ + (((((g << 1) + 1)) ^ xr) << 4));                \
    rp_[2] = *(const f32x4*)(db_ + ((8 + (((g << 1)    ) ^ xr)) << 4));            \
    rp_[3] = *(const f32x4*)(db_ + ((8 + (((g << 1) + 1) ^ xr)) << 4));            \
    } while (0)

#define WAITV(N) do {                                                              \
    asm volatile("s_waitcnt vmcnt(" #N ")" ::: "memory");                          \
    __builtin_amdgcn_sched_barrier(0); } while (0)

#define WAITL0 do {                                                                \
    asm volatile("s_waitcnt lgkmcnt(0)" ::: "memory");                             \
    __builtin_amdgcn_sched_barrier(0); } while (0)

// packed Yt write: 4 j-values are 4 consecutive ushorts in one 16B slot
#define YTWP(ACC, T) do {                                                          \
    int n_ = nb[T] + r0;                                                           \
    if ((T) != 4 || r0 >= 14) {                                                    \
        int xr0_ = sl * 64 + w * 16 + 4 * g;                                       \
        int us_ = n_ * 256 + ((((xr0_ >> 3) ^ (n_ & 31)) << 3) | (xr0_ & 7));      \
        union { __hip_bfloat162 h[2]; uint2 u; } uu_;                              \
        uu_.h[0] = __float22bfloat162_rn(make_float2((ACC)[0], (ACC)[1]));         \
        uu_.h[1] = __float22bfloat162_rn(make_float2((ACC)[2], (ACC)[3]));         \
        *(uint2*)&Yt[us_] = uu_.u;                                                 \
    } } while (0)

__global__ __launch_bounds__(256, 2)
void fno_fused(const float* __restrict__ x, const ushort* __restrict__ T1f,
               const ushort* __restrict__ Ecf, const ushort* __restrict__ Esf,
               ushort* __restrict__ XTb) {
    __shared__ float smx[2][4096];                 // 2 x 16KB superchunk bufs
    __shared__ __align__(16) ushort Yt[16896];     // 33.8 KB unit-swizzled [66][256]
    const int nb[5] = {NB0, NB1, NB2, NB3, NB4};
    const int tid  = threadIdx.x;
    const int lane = tid & 63;
    const int w    = tid >> 6;
    const int r0   = lane & 15;
    const int g    = lane >> 4;
    const int xr   = r0 & 7;
    const int p    = blockIdx.x;                   // plane = b*CIn + i

    bf16x8 bfr[40];
    const bf16x8* bp = (const bf16x8*)T1f;
#pragma unroll
    for (int q = 0; q < 40; ++q) bfr[q] = bp[q * 64 + lane];

    f32x4 rr[2][4];                                // reg double-buffer (static idx)

    STAGE_SC(0); STAGE_SC(1);
    WAITV(4);                                      // superchunk 0 staged
    DSR4(0);

    f32x4 acc0, acc1, acc2, acc3, acc4;
#pragma unroll
    for (int it = 0; it < 16; ++it) {
        if ((it & 3) == 0) {
            acc0 = (f32x4){0,0,0,0}; acc1 = (f32x4){0,0,0,0};
            acc2 = (f32x4){0,0,0,0}; acc3 = (f32x4){0,0,0,0};
            acc4 = (f32x4){0,0,0,0};
        }
        WAITL0;                                    // superchunk it's ds_reads done
        if (it + 2 < 16) STAGE_SC(it + 2);         // overwrite buf[it&1] (safe now)
        if (it <= 13)      { WAITV(4); }           // superchunk it+1 landed
        else if (it == 14) { WAITV(0); }
        if (it < 15) DSR4(it + 1);

        bf16x8 a0v = cvt8(rr[it & 1][0], rr[it & 1][1]);
        bf16x8 a1v = cvt8(rr[it & 1][2], rr[it & 1][3]);
        MFMA5(2 * (it & 3)    , a0v);
        MFMA5(2 * (it & 3) + 1, a1v);

        if ((it & 3) == 3) {                       // strip complete -> Yt (LDS)
            int sl = it >> 2;
            YTWP(acc0, 0); YTWP(acc1, 1); YTWP(acc2, 2); YTWP(acc3, 3); YTWP(acc4, 4);
        }
    }
    __syncthreads();

    // ---- Phase B: P1 = Ec . Yt, P2 = Es . Yt  (M=64 kx, N=66, K=256 x) ----
    const int mt = w;
    f32x4 P1[5], P2[5];
#pragma unroll
    for (int t = 0; t < 5; ++t) { P1[t] = (f32x4){0,0,0,0}; P2[t] = (f32x4){0,0,0,0}; }

    const bf16x8* ecp = (const bf16x8*)Ecf;
    const bf16x8* esp = (const bf16x8*)Esf;
#pragma unroll
    for (int ks = 0; ks < 8; ++ks) {
        bf16x8 ea = ecp[(ks * 4 + mt) * 64 + lane];
        bf16x8 es = esp[(ks * 4 + mt) * 64 + lane];
#pragma unroll
        for (int t = 0; t < 5; ++t) {
            int n = nb[t] + r0;
            bf16x8 b = *(const bf16x8*)&Yt[n * 256 + ((((ks << 2) + g) ^ (n & 31)) << 3)];
            P1[t] = __builtin_amdgcn_mfma_f32_16x16x32_bf16(ea, b, P1[t], 0, 0, 0);
            P2[t] = __builtin_amdgcn_mfma_f32_16x16x32_bf16(es, b, P2[t], 0, 0, 0);
        }
    }

    // recombine re/im across lane pairs, fold weights, stage in LDS, store
    ushort* xtl = (ushort*)&smx[0][0];             // 4224 ushort (spans smx)
#pragma unroll
    for (int t = 0; t < 5; ++t) {
        int n  = nb[t] + r0;
        int ky = n >> 1, im = n & 1;
#pragma unroll
        for (int j = 0; j < 4; ++j) {
            float v2x = __shfl_xor(P2[t][j], 1);
            if (t == 4 && r0 < 14) continue;
            int kx = mt * 16 + 4 * g + j;
            float val = im ? (P1[t][j] + v2x) : (P1[t][j] - v2x);
            float wgt = (kx < 32) ? ((kx == 0 && ky == 0) ? 1.f : 2.f)
                                  : ((ky == 0) ? 0.f : 2.f);
            if (im) wgt = -wgt;                    // fold the (-XTi)*Wi sign
            xtl[kx * 66 + n] = f2bfn(wgt * val);
        }
    }
    __syncthreads();

    const uint4* srcq = (const uint4*)xtl;
    uint4* dstq = (uint4*)(XTb + (size_t)p * 4224);
    for (int e = tid; e < 528; e += 256) dstq[e] = srcq[e];
}

// ---------------------------------------------------------------------------
// K3: out = XTb @ W. Split-K: 704 blocks = (ic 0..31, sc 0..21), K=192
// (6 MFMA steps). W fp32 in fragment order, packed-converted in-register.
// ---------------------------------------------------------------------------
__global__ __launch_bounds__(256)
void fno_gemm3(const ushort* __restrict__ XTb, const float* __restrict__ Wr,
               const float* __restrict__ Wi, float* __restrict__ part) {
    const int blk = blockIdx.x;
    const int ic  = blk / 22;
    const int sc  = blk - ic * 22;
    const int tid = threadIdx.x;
    const int lane = tid & 63;
    const int w    = tid >> 6;
    const int r0   = lane & 15;
    const int g    = lane >> 4;
    const int o    = (w << 4) + r0;

    const float* wrp = Wr + ((size_t)ic * 64 + o) * 2112 + sc * 96 + 4 * g;
    const float* wip = Wi + ((size_t)ic * 64 + o) * 2112 + sc * 96 + 4 * g;
    const ushort* a0 = XTb + ((size_t)r0 * 32 + ic) * 4224 + sc * 192 + 8 * g;
    const ushort* a1 = a0 + (size_t)16 * 32 * 4224;

    f32x4 acc0 = {0,0,0,0}, acc1 = {0,0,0,0};
#pragma unroll
    for (int st = 0; st < 6; ++st) {
        f32x4 vr = *(const f32x4*)(wrp + st * 16);
        f32x4 vi = *(const f32x4*)(wip + st * 16);
        union { __hip_bfloat162 h2[4]; bf16x8 v; } ub;
        ub.h2[0] = __float22bfloat162_rn(make_float2(vr[0], vi[0]));
        ub.h2[1] = __float22bfloat162_rn(make_float2(vr[1], vi[1]));
        ub.h2[2] = __float22bfloat162_rn(make_float2(vr[2], vi[2]));
        ub.h2[3] = __float22bfloat162_rn(make_float2(vr[3], vi[3]));
        bf16x8 af0 = *(const bf16x8*)(a0 + st * 32);
        bf16x8 af1 = *(const bf16x8*)(a1 + st * 32);
        acc0 = __builtin_amdgcn_mfma_f32_16x16x32_bf16(af0, ub.v, acc0, 0, 0, 0);
        acc1 = __builtin_amdgcn_mfma_f32_16x16x32_bf16(af1, ub.v, acc1, 0, 0, 0);
    }

    float* pp = part + (size_t)blk * 2048;
#pragma unroll
    for (int j = 0; j < 4; ++j) {
        pp[(4 * g + j) * 64 + o]      = acc0[j];
        pp[(16 + 4 * g + j) * 64 + o] = acc1[j];
    }
}

// ---------------------------------------------------------------------------
// Parallel reduce: 256 blocks x 256 thr; block owns 8 outputs, 32-way K-split.
// Fixed summation order -> deterministic.
// ---------------------------------------------------------------------------
__global__ __launch_bounds__(256)
void fno_reduce(const float* __restrict__ part, float* __restrict__ out) {
    __shared__ float red[256];
    const int tid = threadIdx.x;
    const int il  = tid & 7;
    const int js  = tid >> 3;                      // 0..31
    const int idx = blockIdx.x * 8 + il;

    float s = 0.f;
#pragma unroll
    for (int t = 0; t < 22; ++t)
        s += part[(size_t)(js + 32 * t) * 2048 + idx];
    red[tid] = s;
    __syncthreads();

    if (tid < 8) {
        float v = 0.f;
#pragma unroll
        for (int q = 0; q < 32; ++q) v += red[q * 8 + tid];
        out[blockIdx.x * 8 + tid] = v;
    }
}

// ---------------------------------------------------------------------------
extern "C" void kernel_launch(void* const* d_in, const int* in_sizes, int n_in,
                              void* d_out, int out_size, void* d_ws, size_t ws_size,
                              hipStream_t stream) {
    const float* x  = (const float*)d_in[0];
    const float* wr = (const float*)d_in[1];
    const float* wi = (const float*)d_in[2];
    float* out = (float*)d_out;
    char* ws   = (char*)d_ws;

    ushort* T1f = (ushort*)(ws + OB_T1F);
    ushort* Ecf = (ushort*)(ws + OB_ECF);
    ushort* Esf = (ushort*)(ws + OB_ESF);
    ushort* XTb = (ushort*)(ws + OB_XTB);
    float* part = (float*)(ws + OB_PART);

    fno_tw<<<80, 256, 0, stream>>>(T1f, Ecf, Esf);
    fno_fused<<<1024, 256, 0, stream>>>(x, T1f, Ecf, Esf, XTb);
    fno_gemm3<<<704, 256, 0, stream>>>(XTb, wr, wi, part);
    fno_reduce<<<256, 256, 0, stream>>>(part, out);
}